// Round 4
// baseline (328.671 us; speedup 1.0000x reference)
//
#include <hip/hip_runtime.h>
#include <math.h>

// Problem constants (fixed by the reference).
#define BSZ  2
#define DOPN 32
#define RAN  128   // D (z)
#define AZI  128   // H (y)
#define ELE  32    // W (x)
#define NVOX (RAN * AZI * ELE)   // 524288 voxels per batch
#define TPB  256
#define VPT  4     // voxels per thread in kernel B (float4 lanes)
#define DCH  8     // DOP chunk: 8 x1-float4 + 8 gum-float4 = 64 VGPRs per burst

__device__ __forceinline__ float sigmoidf_(float t) {
    return 1.0f / (1.0f + __expf(-t));
}

// Kernel A: xyz4[b][n] = {x,y,z,0} cartesian of coords (interleaved for the
// trilinear gather in kernel B).
__global__ __launch_bounds__(TPB) void xyz_precompute(
    const float* __restrict__ coords, float4* __restrict__ xyz4)
{
    const int n = blockIdx.x * TPB + threadIdx.x;
    const int b = blockIdx.y;
    const float* cb = coords + (size_t)b * 3 * NVOX;
    const float r = cb[n];
    const float a = cb[NVOX + n];
    const float e = cb[2 * NVOX + n];
    float sa, ca, se, ce;
    __sincosf(a, &sa, &ca);
    __sincosf(e, &se, &ce);
    xyz4[(size_t)b * NVOX + n] = make_float4(r * ce * ca, r * ce * sa, r * se, 0.0f);
}

// Kernel B. Round-3 post-mortem: compiler sank the DOP loads (VGPR=36) and
// serialized on vmcnt. Here the load burst is FORCED: launch_bounds(,2)
// lifts the VGPR cap to 256, sched_barrier(0) pins all 16 dwordx4 loads
// before any consumption (16 KB in flight per wave).
__global__ __launch_bounds__(TPB, 2) void seg_dop_loss(
    const float* __restrict__ seg, const float* __restrict__ flow,
    const float* __restrict__ x1, const float* __restrict__ dop_arr,
    const float* __restrict__ ori, const float* __restrict__ gumbels,
    const float4* __restrict__ xyz4, float* __restrict__ out)
{
    __shared__ float s_dop[DOPN];
    __shared__ float s_wave[TPB / 64];

    const int b = blockIdx.y;
    if (threadIdx.x < DOPN) s_dop[threadIdx.x] = dop_arr[b * DOPN + threadIdx.x];
    __syncthreads();

    const int n0 = (blockIdx.x * TPB + threadIdx.x) * VPT;
    const size_t base = (size_t)b * DOPN * NVOX + (size_t)n0;

    // ---- DOP axis: argmax(x1+gumbels) + unnormalized softmax(x1)·dop ----
    // x1 ~ N(0,1): exp without max-subtraction is fp32-safe here.
    float m_lg[VPT] = { -3.4e38f, -3.4e38f, -3.4e38f, -3.4e38f };
    float ssum[VPT] = { 0.f, 0.f, 0.f, 0.f };
    float wsum[VPT] = { 0.f, 0.f, 0.f, 0.f };
    int   idx[VPT]  = { 0, 0, 0, 0 };

    #pragma unroll 1                        // chunks reuse the same 64 regs
    for (int h = 0; h < DOPN / DCH; ++h) {
        const size_t dbase = base + (size_t)h * DCH * NVOX;
        float4 xa[DCH], ga[DCH];
        #pragma unroll
        for (int d = 0; d < DCH; ++d)
            xa[d] = *(const float4*)(x1 + dbase + (size_t)d * NVOX);
        #pragma unroll
        for (int d = 0; d < DCH; ++d)
            ga[d] = *(const float4*)(gumbels + dbase + (size_t)d * NVOX);
        __builtin_amdgcn_sched_barrier(0);  // no load may sink past this point
        #pragma unroll
        for (int d = 0; d < DCH; ++d) {
            const int dg = h * DCH + d;
            const float dv = s_dop[dg];
            const float xv[VPT] = { xa[d].x, xa[d].y, xa[d].z, xa[d].w };
            const float gv[VPT] = { ga[d].x, ga[d].y, ga[d].z, ga[d].w };
            #pragma unroll
            for (int v = 0; v < VPT; ++v) {
                const float lg = xv[v] + gv[v];      // TAU = 1.0
                if (lg > m_lg[v]) { m_lg[v] = lg; idx[v] = dg; }
                const float ev = __expf(xv[v]);
                ssum[v] += ev;
                wsum[v] += ev * dv;
            }
        }
    }

    // ---- per-voxel vector loads (all float4) ----
    const float* fl = flow + ((size_t)b * NVOX + (size_t)n0) * 3;
    float fbuf[3 * VPT];
    *(float4*)(fbuf)     = *(const float4*)(fl);
    *(float4*)(fbuf + 4) = *(const float4*)(fl + 4);
    *(float4*)(fbuf + 8) = *(const float4*)(fl + 8);

    const float4* xb4 = xyz4 + (size_t)b * NVOX;
    float4 bxyz[VPT];
    #pragma unroll
    for (int v = 0; v < VPT; ++v) bxyz[v] = xb4[n0 + v];

    const float* ob = ori + (size_t)b * 3 * NVOX;
    const float4 oX4 = *(const float4*)(ob + n0);
    const float4 oY4 = *(const float4*)(ob + NVOX + n0);
    const float4 oZ4 = *(const float4*)(ob + 2 * NVOX + n0);
    const float oX[VPT] = { oX4.x, oX4.y, oX4.z, oX4.w };
    const float oY[VPT] = { oY4.x, oY4.y, oY4.z, oY4.w };
    const float oZ[VPT] = { oZ4.x, oZ4.y, oZ4.z, oZ4.w };

    const float4 sg4 = *(const float4*)(seg + (size_t)b * NVOX + n0);
    const float sg[VPT] = { sg4.x, sg4.y, sg4.z, sg4.w };

    // y,z shared by the 4 consecutive-x voxels (VPT divides ELE).
    const int xB = n0 & (ELE - 1);
    const int yI = (n0 >> 5) & (AZI - 1);
    const int zI = n0 >> 12;

    float contrib = 0.0f;
    #pragma unroll
    for (int v = 0; v < VPT; ++v) {
        const float vx = (float)(xB + v) + fbuf[3 * v + 0];
        const float vy = (float)yI       + fbuf[3 * v + 1];
        const float vz = (float)zI       + fbuf[3 * v + 2];

        // reference's normalized-grid round trip, then border clamp
        const float gx = 2.0f * vx / (float)(ELE - 1) - 1.0f;
        const float gy = 2.0f * vy / (float)(AZI - 1) - 1.0f;
        const float gz = 2.0f * vz / (float)(RAN - 1) - 1.0f;
        const float ix = fminf(fmaxf((gx + 1.0f) * 0.5f * (float)(ELE - 1), 0.0f), (float)(ELE - 1));
        const float iy = fminf(fmaxf((gy + 1.0f) * 0.5f * (float)(AZI - 1), 0.0f), (float)(AZI - 1));
        const float iz = fminf(fmaxf((gz + 1.0f) * 0.5f * (float)(RAN - 1), 0.0f), (float)(RAN - 1));

        const float x0f = floorf(ix), y0f = floorf(iy), z0f = floorf(iz);
        const float wx = ix - x0f, wy = iy - y0f, wz = iz - z0f;
        int x0 = (int)x0f; x0 = x0 < 0 ? 0 : (x0 > ELE - 1 ? ELE - 1 : x0);
        int y0 = (int)y0f; y0 = y0 < 0 ? 0 : (y0 > AZI - 1 ? AZI - 1 : y0);
        int z0 = (int)z0f; z0 = z0 < 0 ? 0 : (z0 > RAN - 1 ? RAN - 1 : z0);
        const int x1c = x0 + 1 > ELE - 1 ? ELE - 1 : x0 + 1;
        const int y1c = y0 + 1 > AZI - 1 ? AZI - 1 : y0 + 1;
        const int z1c = z0 + 1 > RAN - 1 ? RAN - 1 : z0 + 1;

        // 8 independent float4 gathers
        const int m00 = (z0  * AZI + y0 ) * ELE;
        const int m01 = (z0  * AZI + y1c) * ELE;
        const int m10 = (z1c * AZI + y0 ) * ELE;
        const int m11 = (z1c * AZI + y1c) * ELE;
        const float4 c000 = xb4[m00 + x0],  c001 = xb4[m00 + x1c];
        const float4 c010 = xb4[m01 + x0],  c011 = xb4[m01 + x1c];
        const float4 c100 = xb4[m10 + x0],  c101 = xb4[m10 + x1c];
        const float4 c110 = xb4[m11 + x0],  c111 = xb4[m11 + x1c];

        const float w000 = (1.0f - wz) * (1.0f - wy) * (1.0f - wx);
        const float w001 = (1.0f - wz) * (1.0f - wy) * wx;
        const float w010 = (1.0f - wz) * wy * (1.0f - wx);
        const float w011 = (1.0f - wz) * wy * wx;
        const float w100 = wz * (1.0f - wy) * (1.0f - wx);
        const float w101 = wz * (1.0f - wy) * wx;
        const float w110 = wz * wy * (1.0f - wx);
        const float w111 = wz * wy * wx;

        const float sX = w000*c000.x + w001*c001.x + w010*c010.x + w011*c011.x
                       + w100*c100.x + w101*c101.x + w110*c110.x + w111*c111.x;
        const float sY = w000*c000.y + w001*c001.y + w010*c010.y + w011*c011.y
                       + w100*c100.y + w101*c101.y + w110*c110.y + w111*c111.y;
        const float sZ = w000*c000.z + w001*c001.z + w010*c010.z + w011*c011.z
                       + w100*c100.z + w101*c101.z + w110*c110.z + w111*c111.z;

        const float vX = (sX - bxyz[v].x) * 10.0f;   // / INTERVAL(0.1)
        const float vY = (sY - bxyz[v].y) * 10.0f;
        const float vZ = (sZ - bxyz[v].z) * 10.0f;
        const float dop_label = vX * oX[v] + vY * oY[v] + vZ * oZ[v];

        const float dop1 = s_dop[idx[v]];
        const float dop2 = wsum[v] / ssum[v];
        float e1 = dop_label - dop1; e1 *= e1;
        float e2 = dop_label - dop2; e2 *= e2;
        const float seg_label = 0.5f * (sigmoidf_(10.0f * (0.15f - e1)) +
                                        sigmoidf_(10.0f * (0.15f - e2)));
        contrib += fabsf(sigmoidf_(sg[v]) - seg_label);
    }

    // ---- block reduction: wave64 shuffle, then partials in LDS ----
    #pragma unroll
    for (int off = 32; off > 0; off >>= 1)
        contrib += __shfl_down(contrib, off, 64);
    const int lane = threadIdx.x & 63;
    const int wid  = threadIdx.x >> 6;
    if (lane == 0) s_wave[wid] = contrib;
    __syncthreads();
    if (threadIdx.x == 0) {
        float bsum = 0.0f;
        #pragma unroll
        for (int w = 0; w < TPB / 64; ++w) bsum += s_wave[w];
        atomicAdd(out, bsum * (1.0f / ((float)BSZ * (float)NVOX)));
    }
}

extern "C" void kernel_launch(void* const* d_in, const int* in_sizes, int n_in,
                              void* d_out, int out_size, void* d_ws, size_t ws_size,
                              hipStream_t stream) {
    const float* seg    = (const float*)d_in[0];
    const float* flow   = (const float*)d_in[1];
    const float* x1     = (const float*)d_in[2];
    const float* dopar  = (const float*)d_in[3];
    const float* coords = (const float*)d_in[4];
    const float* ori    = (const float*)d_in[5];
    const float* gumb   = (const float*)d_in[6];
    float* out = (float*)d_out;
    float4* xyz4 = (float4*)d_ws;   // BSZ*NVOX*16 B = 16.8 MB

    hipMemsetAsync(d_out, 0, sizeof(float) * (size_t)out_size, stream);

    dim3 gridA(NVOX / TPB, BSZ);
    xyz_precompute<<<gridA, TPB, 0, stream>>>(coords, xyz4);
    dim3 gridB(NVOX / (TPB * VPT), BSZ);
    seg_dop_loss<<<gridB, TPB, 0, stream>>>(seg, flow, x1, dopar, ori, gumb, xyz4, out);
}